// Round 1
// baseline (95.782 us; speedup 1.0000x reference)
//
#include <hip/hip_runtime.h>
#include <math.h>

#define T_STATES 49
#define ROWP 52  // padded row stride (multiple of 4 -> float4-aligned; 52*4=208B, 16B-aligned)

// ws layout: E[49][52] floats (padded cols 49..51 = 0), then ws[49*52] = Tmax

__global__ void prep_kernel(const float* __restrict__ tf, const float* __restrict__ w2,
                            const float* __restrict__ b2, float* __restrict__ ws) {
    __shared__ float red[256];
    const int tid = threadIdx.x;
    const float w0 = w2[0], w1 = w2[1], w2v = w2[2], w3 = w2[3], w4 = w2[4], w5 = w2[5];
    const float bb = b2[0];
    float lmax = -INFINITY;
    for (int idx = tid; idx < T_STATES * T_STATES; idx += 256) {
        const float* p = tf + idx * 6;
        float s = bb + p[0]*w0 + p[1]*w1 + p[2]*w2v + p[3]*w3 + p[4]*w4 + p[5]*w5;
        int j = idx / T_STATES, k = idx - j * T_STATES;
        ws[j * ROWP + k] = s;
        lmax = fmaxf(lmax, s);
    }
    // zero the 3 pad columns of each row
    for (int idx = tid; idx < T_STATES * 3; idx += 256) {
        int j = idx / 3, c = T_STATES + (idx - j * 3);
        ws[j * ROWP + c] = 0.0f;
    }
    red[tid] = lmax;
    __syncthreads();
    for (int s = 128; s > 0; s >>= 1) {
        if (tid < s) red[tid] = fmaxf(red[tid], red[tid + s]);
        __syncthreads();
    }
    const float Tmax = red[0];
    if (tid == 0) ws[T_STATES * ROWP] = Tmax;
    __syncthreads();
    // exponentiate in place (each thread re-reads exactly the slots it wrote)
    for (int idx = tid; idx < T_STATES * T_STATES; idx += 256) {
        int j = idx / T_STATES, k = idx - j * T_STATES;
        float s = ws[j * ROWP + k];
        ws[j * ROWP + k] = __expf(s - Tmax);
    }
}

__global__ __launch_bounds__(64) void crf_fwd(const float* __restrict__ emis,
                                              const float* __restrict__ ws,
                                              float* __restrict__ out, int L) {
    __shared__ __align__(16) float p_s[2][64];
    const int b = blockIdx.x;
    const int lane = threadIdx.x;
    const bool act = lane < T_STATES;
    const int col = act ? (lane + T_STATES - 1) % T_STATES : 0;  // rolled emission index
    const float Tmax = ws[T_STATES * ROWP];

    // Load my E row (row 0 for inactive lanes; results discarded there)
    float4 E[13];
    {
        const float4* Et = (const float4*)ws;
        const int r = act ? lane : 0;
        #pragma unroll
        for (int q = 0; q < 13; ++q) E[q] = Et[r * 13 + q];
    }

    const float* erow = emis + (size_t)b * L * T_STATES;
    float f = act ? (erow[col] + 3.8918202981106265f /* log(49) */) : -INFINITY;

    for (int i = 1; i < L; ++i) {
        float e = act ? erow[i * T_STATES + col] : 0.0f;  // issued early, used late
        // wave-wide max of f
        float m = f;
        #pragma unroll
        for (int off = 32; off >= 1; off >>= 1) m = fmaxf(m, __shfl_xor(m, off, 64));
        float p = __expf(f - m);  // lanes >= 49: exp(-inf)=0 -> pads the 52-wide dot
        float* buf = p_s[i & 1];
        buf[lane] = p;
        __syncthreads();
        const float4* p4 = (const float4*)buf;
        float sum = 0.0f;
        #pragma unroll
        for (int q = 0; q < 13; ++q) {
            float4 pv = p4[q];
            sum += pv.x * E[q].x + pv.y * E[q].y + pv.z * E[q].z + pv.w * E[q].w;
        }
        f = act ? (m + Tmax + __logf(sum) + e) : -INFINITY;
    }

    // final logsumexp over states
    float m2 = f;
    #pragma unroll
    for (int off = 32; off >= 1; off >>= 1) m2 = fmaxf(m2, __shfl_xor(m2, off, 64));
    float s2 = __expf(f - m2);
    #pragma unroll
    for (int off = 32; off >= 1; off >>= 1) s2 += __shfl_xor(s2, off, 64);
    if (lane == 0) out[b] = m2 + __logf(s2);
}

extern "C" void kernel_launch(void* const* d_in, const int* in_sizes, int n_in,
                              void* d_out, int out_size, void* d_ws, size_t ws_size,
                              hipStream_t stream) {
    const float* emis = (const float*)d_in[0];
    const float* tf   = (const float*)d_in[1];
    const float* w2   = (const float*)d_in[2];
    const float* b2   = (const float*)d_in[3];
    float* out = (float*)d_out;
    float* ws  = (float*)d_ws;

    const int B = out_size;                              // 8192
    const int L = in_sizes[0] / (B * T_STATES);          // 48

    prep_kernel<<<1, 256, 0, stream>>>(tf, w2, b2, ws);
    crf_fwd<<<B, 64, 0, stream>>>(emis, ws, out, L);
}

// Round 2
// 72.078 us; speedup vs baseline: 1.3289x; 1.3289x over previous
//
#include <hip/hip_runtime.h>
#include <math.h>

#define T_STATES 49
#define ROWP 52      // padded row stride in floats (13 float4)
#define ROWS_PAD 64  // rows 49..63 are all-zero -> lanes 49..63 self-deactivate

typedef float f32x4 __attribute__((ext_vector_type(4)));

// ws layout: E[64][52] floats (row-major, zero padded), then ws[64*52] = Tmax

__global__ void prep_kernel(const float* __restrict__ tf, const float* __restrict__ w2,
                            const float* __restrict__ b2, float* __restrict__ ws) {
    __shared__ float red[256];
    const int tid = threadIdx.x;
    const float w0 = w2[0], w1 = w2[1], w2v = w2[2], w3 = w2[3], w4 = w2[4], w5 = w2[5];
    const float bb = b2[0];
    float lmax = -INFINITY;
    for (int idx = tid; idx < T_STATES * T_STATES; idx += 256) {
        const float* p = tf + idx * 6;
        float s = bb + p[0]*w0 + p[1]*w1 + p[2]*w2v + p[3]*w3 + p[4]*w4 + p[5]*w5;
        int j = idx / T_STATES, k = idx - j * T_STATES;
        ws[j * ROWP + k] = s;
        lmax = fmaxf(lmax, s);
    }
    // zero all pad slots (rows >= 49, cols >= 49)
    for (int idx = tid; idx < ROWS_PAD * ROWP; idx += 256) {
        int j = idx / ROWP, k = idx - j * ROWP;
        if (j >= T_STATES || k >= T_STATES) ws[idx] = 0.0f;
    }
    red[tid] = lmax;
    __syncthreads();
    for (int s = 128; s > 0; s >>= 1) {
        if (tid < s) red[tid] = fmaxf(red[tid], red[tid + s]);
        __syncthreads();
    }
    const float Tmax = red[0];
    if (tid == 0) ws[ROWS_PAD * ROWP] = Tmax;
    __syncthreads();
    for (int idx = tid; idx < T_STATES * T_STATES; idx += 256) {
        int j = idx / T_STATES, k = idx - j * T_STATES;
        ws[j * ROWP + k] = __expf(ws[j * ROWP + k] - Tmax);
    }
}

__device__ __forceinline__ float wavemax(float x) {
    #pragma unroll
    for (int off = 32; off >= 1; off >>= 1) x = fmaxf(x, __shfl_xor(x, off, 64));
    return x;
}

__global__ __launch_bounds__(256, 5) void crf_fwd(const float* __restrict__ emis,
                                                  const float* __restrict__ ws,
                                                  float* __restrict__ out, int L) {
    __shared__ __align__(16) float p_s[4][2][64];  // [wave][dbuf][lane]
    const int wave = threadIdx.x >> 6;
    const int lane = threadIdx.x & 63;
    const int b = blockIdx.x * 4 + wave;
    const bool act = lane < T_STATES;
    const int col = act ? (lane + T_STATES - 1) % T_STATES : 0;  // rolled emission index
    const float Tmax = ws[ROWS_PAD * ROWP];

    // Load my E row (rows 49..63 are zero -> those lanes' f becomes -inf and stays)
    f32x4 E[13];
    {
        const f32x4* Et = (const f32x4*)ws;
        #pragma unroll
        for (int q = 0; q < 13; ++q) E[q] = Et[lane * 13 + q];
        // Pin E in VGPRs: asm redefinition cannot be rematerialized from memory.
        #pragma unroll
        for (int q = 0; q < 13; ++q) asm volatile("" : "+v"(E[q]));
    }

    const float* erow = emis + (size_t)b * L * T_STATES;
    float f = act ? (erow[col] + 3.8918202981106265f /* log(49) */) : -INFINITY;
    float m = wavemax(f);

    float* const buf0 = &p_s[wave][0][0];
    float* const buf1 = &p_s[wave][1][0];

    float e_next = erow[T_STATES + col];  // emission for step 1, prefetched

    for (int i = 1; i < L; ++i) {
        const float e_cur = e_next;
        // prefetch next step's emission (clamped address on last iter; value unused)
        const float* pnext = (i + 1 < L) ? (erow + (size_t)(i + 1) * T_STATES + col)
                                         : (erow + col);
        e_next = *pnext;

        // deferred max: exact algebra, m is just the subtracted constant
        float a = f - m;
        if (__any(a > 50.0f) || !__any(a > -50.0f)) {
            m = wavemax(f);
            a = f - m;
        }
        const float p = __expf(a);  // lanes >= 49: exp(-inf) = 0 pads the dot

        float* buf = (i & 1) ? buf1 : buf0;
        buf[lane] = p;
        // same-wave DS ops execute in order; wave-private slice -> no barrier
        const f32x4* p4 = (const f32x4*)buf;
        f32x4 acc = {0.0f, 0.0f, 0.0f, 0.0f};
        #pragma unroll
        for (int q = 0; q < 13; ++q) acc += p4[q] * E[q];  // 4 independent FMA chains
        const float sum = (acc.x + acc.y) + (acc.z + acc.w);

        // inactive lanes: sum == 0 -> log -> -inf -> f stays -inf
        f = m + Tmax + __logf(sum) + e_cur;
    }

    // final logsumexp over states
    const float m2 = wavemax(f);
    float s2 = __expf(f - m2);
    #pragma unroll
    for (int off = 32; off >= 1; off >>= 1) s2 += __shfl_xor(s2, off, 64);
    if (lane == 0) out[b] = m2 + __logf(s2);
}

extern "C" void kernel_launch(void* const* d_in, const int* in_sizes, int n_in,
                              void* d_out, int out_size, void* d_ws, size_t ws_size,
                              hipStream_t stream) {
    const float* emis = (const float*)d_in[0];
    const float* tf   = (const float*)d_in[1];
    const float* w2   = (const float*)d_in[2];
    const float* b2   = (const float*)d_in[3];
    float* out = (float*)d_out;
    float* ws  = (float*)d_ws;

    const int B = out_size;                      // 8192
    const int L = in_sizes[0] / (B * T_STATES);  // 48

    prep_kernel<<<1, 256, 0, stream>>>(tf, w2, b2, ws);
    crf_fwd<<<B / 4, 256, 0, stream>>>(emis, ws, out, L);
}

// Round 3
// 71.918 us; speedup vs baseline: 1.3318x; 1.0022x over previous
//
#include <hip/hip_runtime.h>
#include <math.h>

#define T_STATES 49
#define ROWP 52      // padded row stride in floats (13 float4)
#define ROWS_PAD 64  // rows 49..63 all-zero -> lanes 49..63 self-deactivate

typedef float f32x4 __attribute__((ext_vector_type(4)));

// ws layout: E[64][52] floats (row-major, zero padded), then ws[64*52] = Tmax

__global__ void prep_kernel(const float* __restrict__ tf, const float* __restrict__ w2,
                            const float* __restrict__ b2, float* __restrict__ ws) {
    __shared__ float red[256];
    const int tid = threadIdx.x;
    const float w0 = w2[0], w1 = w2[1], w2v = w2[2], w3 = w2[3], w4 = w2[4], w5 = w2[5];
    const float bb = b2[0];
    float lmax = -INFINITY;
    for (int idx = tid; idx < T_STATES * T_STATES; idx += 256) {
        const float* p = tf + idx * 6;
        float s = bb + p[0]*w0 + p[1]*w1 + p[2]*w2v + p[3]*w3 + p[4]*w4 + p[5]*w5;
        int j = idx / T_STATES, k = idx - j * T_STATES;
        ws[j * ROWP + k] = s;
        lmax = fmaxf(lmax, s);
    }
    for (int idx = tid; idx < ROWS_PAD * ROWP; idx += 256) {
        int j = idx / ROWP, k = idx - j * ROWP;
        if (j >= T_STATES || k >= T_STATES) ws[idx] = 0.0f;
    }
    red[tid] = lmax;
    __syncthreads();
    for (int s = 128; s > 0; s >>= 1) {
        if (tid < s) red[tid] = fmaxf(red[tid], red[tid + s]);
        __syncthreads();
    }
    const float Tmax = red[0];
    if (tid == 0) ws[ROWS_PAD * ROWP] = Tmax;
    __syncthreads();
    for (int idx = tid; idx < T_STATES * T_STATES; idx += 256) {
        int j = idx / T_STATES, k = idx - j * T_STATES;
        ws[j * ROWP + k] = __expf(ws[j * ROWP + k] - Tmax);
    }
}

__device__ __forceinline__ float wavemax(float x) {
    #pragma unroll
    for (int off = 32; off >= 1; off >>= 1) x = fmaxf(x, __shfl_xor(x, off, 64));
    return x;
}

__global__ __launch_bounds__(256, 4) void crf_fwd(const float* __restrict__ emis,
                                                  const float* __restrict__ ws,
                                                  float* __restrict__ out, int L) {
    __shared__ __align__(16) float p_s[4][2][64];  // [wave][chain][lane]
    const int wave = threadIdx.x >> 6;
    const int lane = threadIdx.x & 63;
    const int b0 = blockIdx.x * 8 + wave * 2;  // two chains per wave
    const bool act = lane < T_STATES;
    const int col = act ? (lane + T_STATES - 1) % T_STATES : 0;  // rolled emission idx
    const float Tmax = ws[ROWS_PAD * ROWP];

    // E row per lane (rows 49..63 zero -> dead lanes' sum=0 -> log=-inf -> p=0)
    f32x4 E[13];
    {
        const f32x4* Et = (const f32x4*)ws;
        #pragma unroll
        for (int q = 0; q < 13; ++q) E[q] = Et[lane * 13 + q];
        #pragma unroll
        for (int q = 0; q < 13; ++q) asm volatile("" : "+v"(E[q]));  // pin in VGPRs
    }

    const float* erowA = emis + (size_t)b0 * L * T_STATES;
    const float* erowB = erowA + (size_t)L * T_STATES;

    float fA = act ? (erowA[col] + 3.8918202981106265f) : -INFINITY;  // + log(49)
    float fB = act ? (erowB[col] + 3.8918202981106265f) : -INFINITY;
    float mA = wavemax(fA);
    float mB = wavemax(fB);

    float* const bufA = &p_s[wave][0][0];
    float* const bufB = &p_s[wave][1][0];

    float eA = erowA[T_STATES + col];  // step-1 emissions prefetched
    float eB = erowB[T_STATES + col];

    for (int i = 1; i < L; ++i) {
        const float ecA = eA, ecB = eB;
        const int nidx = (i + 1 < L) ? (i + 1) * T_STATES + col : col;
        eA = erowA[nidx];  // prefetch next step (clamped on last iter; unused)
        eB = erowB[nidx];

        // deferred max: exact algebra, m is just the subtracted constant
        float aA = fA - mA, aB = fB - mB;
        if (__any(aA > 50.0f) || __any(aB > 50.0f) ||
            !__any(aA > -50.0f) || !__any(aB > -50.0f)) {
            mA = wavemax(fA); aA = fA - mA;
            mB = wavemax(fB); aB = fB - mB;
        }
        const float pA = __expf(aA);  // dead lanes: exp(-inf)=0 pads the dot
        const float pB = __expf(aB);

        bufA[lane] = pA;
        bufB[lane] = pB;
        // same-wave DS ops are in-order; wave-private slices -> no barrier
        const f32x4* p4A = (const f32x4*)bufA;
        const f32x4* p4B = (const f32x4*)bufB;
        f32x4 accA = {0.0f, 0.0f, 0.0f, 0.0f};
        f32x4 accB = {0.0f, 0.0f, 0.0f, 0.0f};
        #pragma unroll
        for (int q = 0; q < 13; ++q) {
            accA += p4A[q] * E[q];  // 8 independent FMA chains across A/B
            accB += p4B[q] * E[q];
        }
        const float sA = (accA.x + accA.y) + (accA.z + accA.w);
        const float sB = (accB.x + accB.y) + (accB.z + accB.w);

        fA = mA + Tmax + __logf(sA) + ecA;  // dead lanes: log(0)=-inf persists
        fB = mB + Tmax + __logf(sB) + ecB;
    }

    // final logsumexp over states, both chains
    const float m2A = wavemax(fA);
    const float m2B = wavemax(fB);
    float s2A = __expf(fA - m2A);
    float s2B = __expf(fB - m2B);
    #pragma unroll
    for (int off = 32; off >= 1; off >>= 1) {
        s2A += __shfl_xor(s2A, off, 64);
        s2B += __shfl_xor(s2B, off, 64);
    }
    if (lane == 0) {
        out[b0]     = m2A + __logf(s2A);
        out[b0 + 1] = m2B + __logf(s2B);
    }
}

extern "C" void kernel_launch(void* const* d_in, const int* in_sizes, int n_in,
                              void* d_out, int out_size, void* d_ws, size_t ws_size,
                              hipStream_t stream) {
    const float* emis = (const float*)d_in[0];
    const float* tf   = (const float*)d_in[1];
    const float* w2   = (const float*)d_in[2];
    const float* b2   = (const float*)d_in[3];
    float* out = (float*)d_out;
    float* ws  = (float*)d_ws;

    const int B = out_size;                      // 8192
    const int L = in_sizes[0] / (B * T_STATES);  // 48

    prep_kernel<<<1, 256, 0, stream>>>(tf, w2, b2, ws);
    crf_fwd<<<B / 8, 256, 0, stream>>>(emis, ws, out, L);
}

// Round 4
// 70.273 us; speedup vs baseline: 1.3630x; 1.0234x over previous
//
#include <hip/hip_runtime.h>
#include <math.h>

#define TS 49
#define EC 56   // padded E cols (f16) -> 28 h2 pairs per row
#define ER 64   // padded E rows; rows 49..63 zero -> dead lanes self-deactivate
#define LOG49 3.8918202981106265f

typedef _Float16 h2 __attribute__((ext_vector_type(2)));
typedef _Float16 h8 __attribute__((ext_vector_type(8)));

// ws layout: _Float16 E[64][56] (7168 B), then float Tmax at byte 7168

__global__ void prep_kernel(const float* __restrict__ tf, const float* __restrict__ w2,
                            const float* __restrict__ b2, float* __restrict__ ws) {
    __shared__ float tbuf[TS * TS];
    __shared__ float red[256];
    const int tid = threadIdx.x;
    const float w0 = w2[0], w1 = w2[1], w2v = w2[2], w3 = w2[3], w4 = w2[4], w5 = w2[5];
    const float bb = b2[0];
    float lmax = -INFINITY;
    for (int idx = tid; idx < TS * TS; idx += 256) {
        const float* p = tf + idx * 6;
        float s = bb + p[0]*w0 + p[1]*w1 + p[2]*w2v + p[3]*w3 + p[4]*w4 + p[5]*w5;
        tbuf[idx] = s;
        lmax = fmaxf(lmax, s);
    }
    red[tid] = lmax;
    __syncthreads();
    for (int s = 128; s > 0; s >>= 1) {
        if (tid < s) red[tid] = fmaxf(red[tid], red[tid + s]);
        __syncthreads();
    }
    const float Tmax = red[0];
    _Float16* E16 = (_Float16*)ws;
    for (int idx = tid; idx < ER * EC; idx += 256) {
        const int r = idx / EC, c = idx - r * EC;
        const float v = (r < TS && c < TS) ? __expf(tbuf[r * TS + c] - Tmax) : 0.0f;
        E16[idx] = (_Float16)v;
    }
    if (tid == 0) *(float*)((char*)ws + ER * EC * 2) = Tmax;
}

__device__ __forceinline__ float wavemax(float x) {
    #pragma unroll
    for (int off = 32; off >= 1; off >>= 1) x = fmaxf(x, __shfl_xor(x, off, 64));
    return x;
}

__device__ __forceinline__ float dot2acc(h2 a, h2 b, float c) {
#if __has_builtin(__builtin_amdgcn_fdot2)
    return __builtin_amdgcn_fdot2(a, b, c, false);
#else
    return fmaf((float)a.x, (float)b.x, fmaf((float)a.y, (float)b.y, c));
#endif
}

__global__ __launch_bounds__(128, 4) void crf_fwd(const float* __restrict__ emis,
                                                  const void* __restrict__ wsv,
                                                  float* __restrict__ out, int L) {
    __shared__ __align__(16) _Float16 p_s[2][2][64];  // [wave][chain][lane]
    const int wave = threadIdx.x >> 6;
    const int lane = threadIdx.x & 63;
    const int b0 = blockIdx.x * 4 + wave * 2;  // two chains per wave
    const bool act = lane < TS;
    const int col = act ? (lane + TS - 1) % TS : 0;  // rolled emission index
    const float Tmax = *(const float*)((const char*)wsv + ER * EC * 2);

    // E row per lane: 28 h2 (f16 pairs) = 28 VGPRs; rows 49..63 are zero
    h2 E[28];
    {
        const h2* Et = (const h2*)wsv;
        #pragma unroll
        for (int q = 0; q < 28; ++q) E[q] = Et[lane * 28 + q];
        #pragma unroll
        for (int q = 0; q < 28; ++q) asm volatile("" : "+v"(E[q]));
    }

    const float* erowA = emis + (size_t)b0 * L * TS;
    const float* erowB = erowA + (size_t)L * TS;

    float fA = act ? (erowA[col] + LOG49) : -INFINITY;
    float fB = act ? (erowB[col] + LOG49) : -INFINITY;

    _Float16* const bufA = &p_s[wave][0][0];
    _Float16* const bufB = &p_s[wave][1][0];

    float eA = erowA[TS + col];  // step-1 emissions prefetched
    float eB = erowB[TS + col];

    for (int i = 1; i < L; ++i) {
        const float ecA = eA, ecB = eB;
        const int nidx = (i + 1 < L) ? (i + 1) * TS + col : col;  // scalar select + lane col
        eA = erowA[nidx];
        eB = erowB[nidx];

        const float mA = wavemax(fA);
        const float mB = wavemax(fB);
        const float pA = __expf(fA - mA);  // in (0,1] -> f16-safe; dead lanes exp(-inf)=0
        const float pB = __expf(fB - mB);

        bufA[lane] = (_Float16)pA;
        bufB[lane] = (_Float16)pB;
        // same-wave DS ops are in-order; wave-private slices -> no barrier
        const h8* qA = (const h8*)bufA;
        const h8* qB = (const h8*)bufB;
        float a0 = 0.f, a1 = 0.f, a2 = 0.f, a3 = 0.f;
        float b0v = 0.f, b1v = 0.f, b2v = 0.f, b3v = 0.f;
        #pragma unroll
        for (int q = 0; q < 7; ++q) {  // 7 x ds_read_b128 per chain, uniform -> broadcast
            const h8 vA = qA[q];
            const h8 vB = qB[q];
            a0 = dot2acc(__builtin_shufflevector(vA, vA, 0, 1), E[4*q + 0], a0);
            a1 = dot2acc(__builtin_shufflevector(vA, vA, 2, 3), E[4*q + 1], a1);
            a2 = dot2acc(__builtin_shufflevector(vA, vA, 4, 5), E[4*q + 2], a2);
            a3 = dot2acc(__builtin_shufflevector(vA, vA, 6, 7), E[4*q + 3], a3);
            b0v = dot2acc(__builtin_shufflevector(vB, vB, 0, 1), E[4*q + 0], b0v);
            b1v = dot2acc(__builtin_shufflevector(vB, vB, 2, 3), E[4*q + 1], b1v);
            b2v = dot2acc(__builtin_shufflevector(vB, vB, 4, 5), E[4*q + 2], b2v);
            b3v = dot2acc(__builtin_shufflevector(vB, vB, 6, 7), E[4*q + 3], b3v);
        }
        const float sA = (a0 + a1) + (a2 + a3);
        const float sB = (b0v + b1v) + (b2v + b3v);

        // dead lanes: sum==0 -> log=-inf -> f stays -inf
        fA = mA + Tmax + __logf(sA) + ecA;
        fB = mB + Tmax + __logf(sB) + ecB;
    }

    // final logsumexp over states, both chains
    const float m2A = wavemax(fA);
    const float m2B = wavemax(fB);
    float s2A = __expf(fA - m2A);
    float s2B = __expf(fB - m2B);
    #pragma unroll
    for (int off = 32; off >= 1; off >>= 1) {
        s2A += __shfl_xor(s2A, off, 64);
        s2B += __shfl_xor(s2B, off, 64);
    }
    if (lane == 0) {
        out[b0]     = m2A + __logf(s2A);
        out[b0 + 1] = m2B + __logf(s2B);
    }
}

extern "C" void kernel_launch(void* const* d_in, const int* in_sizes, int n_in,
                              void* d_out, int out_size, void* d_ws, size_t ws_size,
                              hipStream_t stream) {
    const float* emis = (const float*)d_in[0];
    const float* tf   = (const float*)d_in[1];
    const float* w2   = (const float*)d_in[2];
    const float* b2   = (const float*)d_in[3];
    float* out = (float*)d_out;
    float* ws  = (float*)d_ws;

    const int B = out_size;                      // 8192
    const int L = in_sizes[0] / (B * TS);        // 48

    prep_kernel<<<1, 256, 0, stream>>>(tf, w2, b2, ws);
    crf_fwd<<<B / 4, 128, 0, stream>>>(emis, (const void*)ws, out, L);
}

// Round 5
// 49.543 us; speedup vs baseline: 1.9333x; 1.4184x over previous
//
#include <hip/hip_runtime.h>
#include <math.h>

#define TS 49
#define LOG49 3.8918202981106265f
#define LN2 0.6931471805599453f

typedef short bf16x8 __attribute__((ext_vector_type(8)));  // 8 bf16 = 4 VGPRs
typedef float f32x4 __attribute__((ext_vector_type(4)));

// ws layout:
//   bytes [0, 8192):  B-fragments, bf16[nt=4][h=2][lane=64][8]
//                     value = exp(trans[j][k]-Tmax), j = nt*16+(lane&15),
//                     k = h*32+(lane>>4)*8+s  (zero outside 49x49)
//   byte 8192: float Tmax

__global__ void prep_kernel(const float* __restrict__ tf, const float* __restrict__ w2,
                            const float* __restrict__ b2, float* __restrict__ ws) {
    __shared__ float tr[TS * TS];
    __shared__ float red[256];
    const int tid = threadIdx.x;
    const float w0 = w2[0], w1 = w2[1], w2v = w2[2], w3 = w2[3], w4 = w2[4], w5 = w2[5];
    const float bb = b2[0];
    float lmax = -INFINITY;
    for (int idx = tid; idx < TS * TS; idx += 256) {
        const float* p = tf + idx * 6;
        float s = bb + p[0]*w0 + p[1]*w1 + p[2]*w2v + p[3]*w3 + p[4]*w4 + p[5]*w5;
        tr[idx] = s;
        lmax = fmaxf(lmax, s);
    }
    red[tid] = lmax;
    __syncthreads();
    for (int s = 128; s > 0; s >>= 1) {
        if (tid < s) red[tid] = fmaxf(red[tid], red[tid + s]);
        __syncthreads();
    }
    const float Tmax = red[0];
    __syncthreads();
    unsigned short* B = (unsigned short*)ws;
    for (int idx = tid; idx < 4096; idx += 256) {
        const int s  = idx & 7;
        const int l  = (idx >> 3) & 63;
        const int h  = (idx >> 9) & 1;
        const int nt = idx >> 10;
        const int j = nt * 16 + (l & 15);
        const int k = h * 32 + (l >> 4) * 8 + s;
        float v = (j < TS && k < TS) ? __expf(tr[j * TS + k] - Tmax) : 0.0f;
        unsigned bts = __float_as_uint(v);
        B[idx] = (unsigned short)((bts + 0x7FFFu + ((bts >> 16) & 1u)) >> 16);  // rne bf16
    }
    if (tid == 0) ((float*)ws)[2048] = Tmax;  // byte 8192
}

// One wave = 16 chains. V kept in MFMA C-layout regs v[nt][t]:
//   chain row r = 4*(lane>>4)+t, state j = nt*16+(lane&15).
// A-layout needed next step: chain = lane&15, k = h*32+(lane>>4)*8+[0..7].
// LDS V16 swizzled so A-reads are linear b128: idx16 = ((j>>3)*16 + chain)*8 + (j&7).
__global__ __launch_bounds__(64, 2) void crf_fwd(const float* __restrict__ emis,
                                                 const unsigned short* __restrict__ wsB,
                                                 float* __restrict__ out, int L) {
    __shared__ __align__(16) unsigned short V16[1024];  // 16 chains x 64 states bf16
    const int l  = threadIdx.x;
    const int g  = l >> 4;
    const int c0 = l & 15;
    const int b0 = blockIdx.x * 16;
    const float Tmax = ((const float*)wsB)[2048];

    // B fragments: register-resident all kernel (32 VGPRs)
    bf16x8 Bf[8];
    {
        const bf16x8* Bt = (const bf16x8*)wsB;
        #pragma unroll
        for (int q = 0; q < 8; ++q) Bf[q] = Bt[q * 64 + l];
    }

    // emission base pointers (4 chains per lane: rows 4g+t) and rolled cols
    const float* eb[4];
    #pragma unroll
    for (int t = 0; t < 4; ++t) eb[t] = emis + (size_t)(b0 + 4 * g + t) * L * TS;
    int jp[4];
    #pragma unroll
    for (int nt = 0; nt < 4; ++nt) jp[nt] = (nt * 16 + c0 + 48) % 49;

    // init: V_0 = exp(emit[:,0,:]) in C layout (pads = 0)
    float v[4][4];
    #pragma unroll
    for (int nt = 0; nt < 4; ++nt) {
        const bool actj = (nt * 16 + c0) < TS;
        #pragma unroll
        for (int t = 0; t < 4; ++t) v[nt][t] = actj ? __expf(eb[t][jp[nt]]) : 0.0f;
    }

    // depth-2 emission prefetch
    float pfA[4][4], pfB[4][4];
    #pragma unroll
    for (int nt = 0; nt < 4; ++nt)
        #pragma unroll
        for (int t = 0; t < 4; ++t) {
            pfA[nt][t] = eb[t][1 * TS + jp[nt]];
            pfB[nt][t] = eb[t][2 * TS + jp[nt]];
        }

    float sc[4] = {0.f, 0.f, 0.f, 0.f};

#define STEP(I, PF, RENORM) do {                                                      \
    _Pragma("unroll")                                                                 \
    for (int nt = 0; nt < 4; ++nt) {                                                  \
        const int base = ((nt * 2 + (c0 >> 3)) * 16) * 8 + (c0 & 7);                  \
        _Pragma("unroll")                                                             \
        for (int t = 0; t < 4; ++t) {                                                 \
            unsigned bts = __float_as_uint(v[nt][t]);                                 \
            V16[base + (4 * g + t) * 8] =                                             \
                (unsigned short)((bts + 0x7FFFu + ((bts >> 16) & 1u)) >> 16);         \
        }                                                                             \
    }                                                                                 \
    float ee[4][4];                                                                   \
    _Pragma("unroll")                                                                 \
    for (int nt = 0; nt < 4; ++nt)                                                    \
        _Pragma("unroll")                                                             \
        for (int t = 0; t < 4; ++t) ee[nt][t] = __expf(PF[nt][t]);                    \
    if ((I) + 2 < L) {                                                                \
        const int off = ((I) + 2) * TS;                                               \
        _Pragma("unroll")                                                             \
        for (int nt = 0; nt < 4; ++nt)                                                \
            _Pragma("unroll")                                                         \
            for (int t = 0; t < 4; ++t) PF[nt][t] = eb[t][off + jp[nt]];              \
    }                                                                                 \
    asm volatile("" ::: "memory"); /* order LDS writes before reads */                \
    bf16x8 A0, A1;                                                                    \
    {                                                                                 \
        const bf16x8* Vv = (const bf16x8*)V16;                                        \
        A0 = Vv[g * 16 + c0];                                                         \
        A1 = Vv[(4 + g) * 16 + c0];                                                   \
    }                                                                                 \
    _Pragma("unroll")                                                                 \
    for (int nt = 0; nt < 4; ++nt) {                                                  \
        f32x4 acc = {0.f, 0.f, 0.f, 0.f};                                             \
        acc = __builtin_amdgcn_mfma_f32_16x16x32_bf16(A0, Bf[2 * nt],     acc, 0, 0, 0); \
        acc = __builtin_amdgcn_mfma_f32_16x16x32_bf16(A1, Bf[2 * nt + 1], acc, 0, 0, 0); \
        _Pragma("unroll")                                                             \
        for (int t = 0; t < 4; ++t) v[nt][t] = acc[t] * ee[nt][t];                    \
    }                                                                                 \
    if (RENORM) {                                                                     \
        _Pragma("unroll")                                                             \
        for (int t = 0; t < 4; ++t) {                                                 \
            float mx = fmaxf(fmaxf(v[0][t], v[1][t]), fmaxf(v[2][t], v[3][t]));       \
            mx = fmaxf(mx, __shfl_xor(mx, 1, 64));                                    \
            mx = fmaxf(mx, __shfl_xor(mx, 2, 64));                                    \
            mx = fmaxf(mx, __shfl_xor(mx, 4, 64));                                    \
            mx = fmaxf(mx, __shfl_xor(mx, 8, 64));                                    \
            const unsigned ex = __float_as_uint(mx) >> 23;                            \
            const float fac = __uint_as_float((254u - ex) << 23);                     \
            sc[t] += (float)((int)ex - 127) * LN2;                                    \
            _Pragma("unroll")                                                         \
            for (int nt = 0; nt < 4; ++nt) v[nt][t] *= fac;                           \
        }                                                                             \
    }                                                                                 \
} while (0)

    int i = 1;
    for (; i + 1 < L; i += 2) {
        STEP(i, pfA, 1);      // odd step: renorm
        STEP(i + 1, pfB, 0);  // even step: no renorm
    }
    if (i < L) STEP(i, pfA, 1);  // tail (i = L-1 odd)
#undef STEP

    // final: alpha[c] = sc + log(sum_j V) + log49 + (L-1)*Tmax
    float res[4];
    #pragma unroll
    for (int t = 0; t < 4; ++t) {
        float s = (v[0][t] + v[1][t]) + (v[2][t] + v[3][t]);
        s += __shfl_xor(s, 1, 64);
        s += __shfl_xor(s, 2, 64);
        s += __shfl_xor(s, 4, 64);
        s += __shfl_xor(s, 8, 64);
        res[t] = sc[t] + __logf(s) + LOG49 + (float)(L - 1) * Tmax;
    }
    if (c0 == 0) {
        #pragma unroll
        for (int t = 0; t < 4; ++t) out[b0 + 4 * g + t] = res[t];
    }
}

extern "C" void kernel_launch(void* const* d_in, const int* in_sizes, int n_in,
                              void* d_out, int out_size, void* d_ws, size_t ws_size,
                              hipStream_t stream) {
    const float* emis = (const float*)d_in[0];
    const float* tf   = (const float*)d_in[1];
    const float* w2   = (const float*)d_in[2];
    const float* b2   = (const float*)d_in[3];
    float* out = (float*)d_out;
    float* ws  = (float*)d_ws;

    const int B = out_size;                // 8192
    const int L = in_sizes[0] / (B * TS);  // 48

    prep_kernel<<<1, 256, 0, stream>>>(tf, w2, b2, ws);
    crf_fwd<<<B / 16, 64, 0, stream>>>(emis, (const unsigned short*)ws, out, L);
}